// Round 6
// baseline (391.562 us; speedup 1.0000x reference)
//
#include <hip/hip_runtime.h>
#include <hip/hip_bf16.h>
#include <math.h>

// ConvNeXt MLP + parallel MoE-LoRA, fp32 in/out, bf16-tolerance harness.
// B,H,W,C = 64,14,14,768 ; N_tok = 12544 = 98*128 ; HID = 3072 ; E=8,K=2,R=16.
//
//   h  = gelu(x @ w1 + b1)          \  merged: GEMM1 [12544,768]x[768,3200]
//   sd = wt * gelu(x @ wdown)       /  (wdt stacked under w1t; 25th n-tile)
//   out = [h | sd] @ [w2 ; wup] + b2   GEMM2 [12544,3200]x[3200,768]
//
// R6: GEMM core reverted to the PROVEN R3 staging: BK=32, contiguous global
//     source, 64-B LDS row stride (2-bank = free; R5's 128-B stride was
//     1-bank -> conflicts x3, FETCH x2, 110->172 us). Keep prep fusion +
//     LoRA fold. Clean test: GEMM2 TN=64 (1176 active blocks = 4.6/CU vs
//     2.3/CU at TN=128 — launch-width was GEMM2's occupancy cap).

#define NTOK   12544
#define CDIM   768
#define HIDDIM 3072
#define KBIG   3200

typedef __attribute__((ext_vector_type(8))) short bf16x8;
typedef __attribute__((ext_vector_type(4))) float f32x4;

#define GLOBAL_AS(p) ((const __attribute__((address_space(1))) void*)(p))
#define LDS_AS(p)    ((__attribute__((address_space(3))) void*)(p))

__device__ inline unsigned short f2bf(float f) {
    unsigned int x = __float_as_uint(f);
    x += 0x7fffu + ((x >> 16) & 1u);   // RNE
    return (unsigned short)(x >> 16);
}

// tanh-form GELU, branch-free; max |err| ~4.3e-4 vs exact erf form.
__device__ inline float gelu_fast(float x) {
    float x3 = x * x * x;
    float u2 = 1.5957691216057308f * x + 0.07135481627260025f * x3;
    float e = __expf(-u2);
    return x * __builtin_amdgcn_rcpf(1.0f + e);
}

// ---------------- fused prep: cast_x + 3 transposes + pack_wdown ----------------
__global__ void __launch_bounds__(256) prep_kernel(
        const float* __restrict__ x, const float* __restrict__ w1,
        const float* __restrict__ w2, const float* __restrict__ wup,
        const float* __restrict__ wdn,
        unsigned short* __restrict__ xb, unsigned short* __restrict__ w1t,
        unsigned short* __restrict__ B2t, unsigned short* __restrict__ wdt) {
    __shared__ float tile[32][33];
    const int b = blockIdx.x, tid = threadIdx.x;
    if (b < 9408) {                      // cast x -> bf16, float4->ushort4
        int i = b * 256 + tid;
        float4 v = ((const float4*)x)[i];
        ushort4 o;
        o.x = f2bf(v.x); o.y = f2bf(v.y); o.z = f2bf(v.z); o.w = f2bf(v.w);
        ((ushort4*)xb)[i] = o;
        return;
    }
    if (b < 14112) {                     // 32x32 transpose tiles
        const float* in; unsigned short* outp; int Ccols, out_ld, out_off, bx, by;
        if (b < 11712) { int t = b - 9408;  in = w1;  outp = w1t; Ccols = 3072; out_ld = 768;  out_off = 0;    bx = t % 96; by = t / 96; }
        else if (b < 14016) { int t = b - 11712; in = w2;  outp = B2t; Ccols = 768;  out_ld = 3200; out_off = 0;    bx = t % 24; by = t / 24; }
        else { int t = b - 14016; in = wup; outp = B2t; Ccols = 768;  out_ld = 3200; out_off = 3072; bx = t % 24; by = t / 24; }
        int c0 = bx * 32, r0 = by * 32;
        int tx = tid & 31, ty = tid >> 5;
        for (int i = ty; i < 32; i += 8)
            tile[i][tx] = in[(size_t)(r0 + i) * Ccols + c0 + tx];
        __syncthreads();
        for (int i = ty; i < 32; i += 8)
            outp[(size_t)(c0 + i) * out_ld + out_off + r0 + tx] = f2bf(tile[tx][i]);
        return;
    }
    {   // pack_wdown: wdt[j][c] = wdown[e][c][r], j = e*16+r
        int idx = (b - 14112) * 256 + tid;
        int j = idx / 768, c = idx - j * 768;
        int e = j >> 4, r = j & 15;
        wdt[idx] = f2bf(wdn[((size_t)e * 768 + c) * 16 + r]);
    }
}

// ------------- MFMA GEMM, C = A * Bt^T, 128M x TN, BK=32 (R3-proven core) -----
// EPI 0: TN=128, grid(25,98). bx<24: gelu(acc+b1)->bf16 Ap ; bx==24: LoRA tile.
// EPI 2: TN=64, 1-D XCD-swizzled grid. acc + b2 -> f32 out.

template <int EPI, int TN>
__global__ void __launch_bounds__(256)
gemm_bt_kernel(const unsigned short* __restrict__ A, int lda,
               const unsigned short* __restrict__ Bt, int ldb,
               int kIters,
               const float* __restrict__ bias,
               unsigned short* __restrict__ apOut,
               float* __restrict__ fOut,
               const int* __restrict__ tki,
               const float* __restrict__ tkp) {
    __shared__ __align__(16) unsigned short As[128 * 32];
    __shared__ __align__(16) unsigned short Bs[TN * 32];

    int bx, by;
    if (EPI == 2) {
        // 1248 blocks; same-m-row blocks share L&7 (same XCD, consecutive).
        int L = blockIdx.x;
        int k = L & 7, t = L >> 3;
        bx = t % 12;
        by = (t / 12) * 8 + k;
        if (by >= NTOK / 128) return;      // block-uniform, pre-barrier safe
    } else {
        bx = blockIdx.x;
        by = blockIdx.y;
    }

    const int tid  = threadIdx.x;
    const int wave = tid >> 6;
    const int lane = tid & 63;
    const int m0 = by * 128;
    const int n0 = bx * TN;
    const int NI = TN / 32;                    // 4 for TN=128, 2 for TN=64
    const int wm = (wave >> 1) * 64;
    const int wn = (wave & 1) * (TN / 2);
    const int row16 = lane & 15;
    const int quad  = lane >> 4;
    const int kch   = quad * 8;

    f32x4 acc[4][TN / 32] = {};

    // Staging: ci = q*256 + tid covers a [rows][32] tile row-major
    // (row = ci>>2, kcol = (ci&3)*8); global source contiguous in lane order;
    // LDS dest = wave-uniform base + lane*16B = &tile[ci*8]. 64-B row stride.
    const int r_s = tid >> 2;
    const int c_s = (tid & 3) * 8;
    const size_t aRow0 = (size_t)(m0 + r_s) * lda + c_s;
    const size_t aRow1 = aRow0 + (size_t)64 * lda;
    const size_t bRow0 = (size_t)(n0 + r_s) * ldb + c_s;
    const size_t bRow1 = bRow0 + (size_t)64 * ldb;
    unsigned short* asBase0 = &As[(wave * 64) * 8];
    unsigned short* asBase1 = &As[(256 + wave * 64) * 8];
    unsigned short* bsBase0 = &Bs[(wave * 64) * 8];
    unsigned short* bsBase1 = &Bs[(256 + wave * 64) * 8];

    for (int kt = 0; kt < kIters; ++kt) {
        const int k0 = kt * 32;
        __builtin_amdgcn_global_load_lds(GLOBAL_AS(A + aRow0 + k0), LDS_AS(asBase0), 16, 0, 0);
        __builtin_amdgcn_global_load_lds(GLOBAL_AS(A + aRow1 + k0), LDS_AS(asBase1), 16, 0, 0);
        __builtin_amdgcn_global_load_lds(GLOBAL_AS(Bt + bRow0 + k0), LDS_AS(bsBase0), 16, 0, 0);
        if (TN == 128)
            __builtin_amdgcn_global_load_lds(GLOBAL_AS(Bt + bRow1 + k0), LDS_AS(bsBase1), 16, 0, 0);
        __syncthreads();

        bf16x8 af[4], bfr[TN / 32];
        #pragma unroll
        for (int mi = 0; mi < 4; ++mi)
            af[mi] = *(const bf16x8*)&As[(wm + mi * 16 + row16) * 32 + kch];
        #pragma unroll
        for (int ni = 0; ni < NI; ++ni)
            bfr[ni] = *(const bf16x8*)&Bs[(wn + ni * 16 + row16) * 32 + kch];

        #pragma unroll
        for (int mi = 0; mi < 4; ++mi)
            #pragma unroll
            for (int ni = 0; ni < NI; ++ni)
                acc[mi][ni] = __builtin_amdgcn_mfma_f32_16x16x32_bf16(
                    af[mi], bfr[ni], acc[mi][ni], 0, 0, 0);
        __syncthreads();
    }

    const bool lora = (EPI == 0) && (bx == 24);

    // epilogue: lane holds col = row16 (+16*ni), rows quad*4 + i
    #pragma unroll
    for (int mi = 0; mi < 4; ++mi) {
        #pragma unroll
        for (int i = 0; i < 4; ++i) {
            const int m = m0 + wm + mi * 16 + quad * 4 + i;
            int i0 = 0, i1 = 0; float p0 = 0.f, p1 = 0.f;
            if (EPI == 0 && lora) {
                i0 = tki[m * 2]; i1 = tki[m * 2 + 1];
                p0 = tkp[m * 2]; p1 = tkp[m * 2 + 1];
            }
            #pragma unroll
            for (int ni = 0; ni < NI; ++ni) {
                const int ncol = n0 + wn + ni * 16 + row16;
                float v = acc[mi][ni][i];
                if (EPI == 0) {
                    if (lora) {
                        const int e = (ncol >> 4) - 192;   // (ncol-3072)/16
                        float wt = (i0 == e ? p0 : 0.f) + (i1 == e ? p1 : 0.f);
                        v = gelu_fast(v) * wt;
                    } else {
                        v = gelu_fast(v + bias[ncol]);
                    }
                    apOut[(size_t)m * KBIG + ncol] = f2bf(v);
                } else {
                    fOut[(size_t)m * CDIM + ncol] = v + bias[ncol];
                }
            }
        }
    }
}

// ---------------- launch ----------------

extern "C" void kernel_launch(void* const* d_in, const int* in_sizes, int n_in,
                              void* d_out, int out_size, void* d_ws, size_t ws_size,
                              hipStream_t stream) {
    const float* x   = (const float*)d_in[0];
    const float* tkp = (const float*)d_in[1];
    const int*   tki = (const int*)d_in[2];
    const float* w1  = (const float*)d_in[3];
    const float* b1  = (const float*)d_in[4];
    const float* w2  = (const float*)d_in[5];
    const float* b2  = (const float*)d_in[6];
    const float* wdn = (const float*)d_in[7];
    const float* wup = (const float*)d_in[8];
    float* out = (float*)d_out;

    unsigned short* xb  = (unsigned short*)d_ws;
    unsigned short* w1t = xb  + (size_t)NTOK * CDIM;      // 3200 rows x 768 (w1t | wdt)
    unsigned short* wdt = w1t + (size_t)HIDDIM * CDIM;    // rows 3072..3199
    unsigned short* B2t = w1t + (size_t)KBIG * CDIM;      // 768 x 3200
    unsigned short* Ap  = B2t + (size_t)CDIM * KBIG;      // 12544 x 3200

    prep_kernel<<<dim3(14496), 256, 0, stream>>>(x, w1, w2, wup, wdn,
                                                 xb, w1t, B2t, wdt);

    // GEMM1 (+LoRA down tile): grid 25x98, K=768 -> 24 BK32 iters
    gemm_bt_kernel<0, 128><<<dim3(25, NTOK / 128), 256, 0, stream>>>(
        xb, CDIM, w1t, CDIM, CDIM / 32, b1, Ap, nullptr, tki, tkp);

    // GEMM2: out = Ap @ B2t^T + b2 ; K=3200 -> 100 BK32 iters; XCD-swizzled grid
    gemm_bt_kernel<2, 64><<<dim3(1248), 256, 0, stream>>>(
        Ap, KBIG, B2t, KBIG, KBIG / 32, b2, nullptr, out, nullptr, nullptr);
}

// Round 7
// 386.774 us; speedup vs baseline: 1.0124x; 1.0124x over previous
//
#include <hip/hip_runtime.h>
#include <hip/hip_bf16.h>
#include <math.h>

// ConvNeXt MLP + parallel MoE-LoRA, fp32 in/out, bf16-tolerance harness.
// B,H,W,C = 64,14,14,768 ; N_tok = 12544 = 98*128 ; HID = 3072 ; E=8,K=2,R=16.
//
//   h  = gelu(x @ w1 + b1)          \  merged: GEMM1 [12544,768]x[768,3200]
//   sd = wt * gelu(x @ wdown)       /  (wdt stacked under w1t)
//   out = [h | sd] @ [w2 ; wup] + b2   GEMM2 [12544,3200]x[3200,768]
//
// R7: ROOT CAUSE of R4-R6 GEMM1 regression was grid WIDTH 25 (not the LDS
//     swizzle): with x-fast dispatch + round-robin XCD, width%8==0 pins
//     same-B-strip blocks to one XCD (FETCH 84 MB); width 25 breaks it
//     (175 MB, latency-bound). Fix: grid (24,103) — LoRA tile folded as
//     TAIL Y-ROWS remapped to bx=24, preserving the aligned 24-wide order
//     for the main 2352 blocks. GEMM2 stays TN=64+swizzle for a clean read.

#define NTOK   12544
#define CDIM   768
#define HIDDIM 3072
#define KBIG   3200

typedef __attribute__((ext_vector_type(8))) short bf16x8;
typedef __attribute__((ext_vector_type(4))) float f32x4;

#define GLOBAL_AS(p) ((const __attribute__((address_space(1))) void*)(p))
#define LDS_AS(p)    ((__attribute__((address_space(3))) void*)(p))

__device__ inline unsigned short f2bf(float f) {
    unsigned int x = __float_as_uint(f);
    x += 0x7fffu + ((x >> 16) & 1u);   // RNE
    return (unsigned short)(x >> 16);
}

// tanh-form GELU, branch-free; max |err| ~4.3e-4 vs exact erf form.
__device__ inline float gelu_fast(float x) {
    float x3 = x * x * x;
    float u2 = 1.5957691216057308f * x + 0.07135481627260025f * x3;
    float e = __expf(-u2);
    return x * __builtin_amdgcn_rcpf(1.0f + e);
}

// ---------------- fused prep: cast_x + 3 transposes + pack_wdown ----------------
__global__ void __launch_bounds__(256) prep_kernel(
        const float* __restrict__ x, const float* __restrict__ w1,
        const float* __restrict__ w2, const float* __restrict__ wup,
        const float* __restrict__ wdn,
        unsigned short* __restrict__ xb, unsigned short* __restrict__ w1t,
        unsigned short* __restrict__ B2t, unsigned short* __restrict__ wdt) {
    __shared__ float tile[32][33];
    const int b = blockIdx.x, tid = threadIdx.x;
    if (b < 9408) {                      // cast x -> bf16, float4->ushort4
        int i = b * 256 + tid;
        float4 v = ((const float4*)x)[i];
        ushort4 o;
        o.x = f2bf(v.x); o.y = f2bf(v.y); o.z = f2bf(v.z); o.w = f2bf(v.w);
        ((ushort4*)xb)[i] = o;
        return;
    }
    if (b < 14112) {                     // 32x32 transpose tiles
        const float* in; unsigned short* outp; int Ccols, out_ld, out_off, bx, by;
        if (b < 11712) { int t = b - 9408;  in = w1;  outp = w1t; Ccols = 3072; out_ld = 768;  out_off = 0;    bx = t % 96; by = t / 96; }
        else if (b < 14016) { int t = b - 11712; in = w2;  outp = B2t; Ccols = 768;  out_ld = 3200; out_off = 0;    bx = t % 24; by = t / 24; }
        else { int t = b - 14016; in = wup; outp = B2t; Ccols = 768;  out_ld = 3200; out_off = 3072; bx = t % 24; by = t / 24; }
        int c0 = bx * 32, r0 = by * 32;
        int tx = tid & 31, ty = tid >> 5;
        for (int i = ty; i < 32; i += 8)
            tile[i][tx] = in[(size_t)(r0 + i) * Ccols + c0 + tx];
        __syncthreads();
        for (int i = ty; i < 32; i += 8)
            outp[(size_t)(c0 + i) * out_ld + out_off + r0 + tx] = f2bf(tile[tx][i]);
        return;
    }
    {   // pack_wdown: wdt[j][c] = wdown[e][c][r], j = e*16+r
        int idx = (b - 14112) * 256 + tid;
        int j = idx / 768, c = idx - j * 768;
        int e = j >> 4, r = j & 15;
        wdt[idx] = f2bf(wdn[((size_t)e * 768 + c) * 16 + r]);
    }
}

// ------------- MFMA GEMM, C = A * Bt^T, 128M x TN, BK=32 (R3-proven core) -----
// EPI 0: TN=128, grid(24,103). by<98: main tile bx in [0,24). by>=98: remap to
//        LoRA tile (bx=24, by=(by-98)*24+bx) — keeps main order 24-aligned.
// EPI 2: TN=64, 1-D XCD-swizzled grid. acc + b2 -> f32 out.

template <int EPI, int TN>
__global__ void __launch_bounds__(256)
gemm_bt_kernel(const unsigned short* __restrict__ A, int lda,
               const unsigned short* __restrict__ Bt, int ldb,
               int kIters,
               const float* __restrict__ bias,
               unsigned short* __restrict__ apOut,
               float* __restrict__ fOut,
               const int* __restrict__ tki,
               const float* __restrict__ tkp) {
    __shared__ __align__(16) unsigned short As[128 * 32];
    __shared__ __align__(16) unsigned short Bs[TN * 32];

    int bx, by;
    if (EPI == 2) {
        // 1248 blocks; same-m-row blocks share L&7 (same XCD, consecutive).
        int L = blockIdx.x;
        int k = L & 7, t = L >> 3;
        bx = t % 12;
        by = (t / 12) * 8 + k;
        if (by >= NTOK / 128) return;      // block-uniform, pre-barrier safe
    } else {
        bx = blockIdx.x;
        by = blockIdx.y;
        if (by >= 98) {                    // LoRA tail rows -> bx=24 tile
            int lby = (by - 98) * 24 + bx;
            if (lby >= 98) return;         // block-uniform, pre-barrier safe
            by = lby; bx = 24;
        }
    }

    const int tid  = threadIdx.x;
    const int wave = tid >> 6;
    const int lane = tid & 63;
    const int m0 = by * 128;
    const int n0 = bx * TN;
    const int NI = TN / 32;                    // 4 for TN=128, 2 for TN=64
    const int wm = (wave >> 1) * 64;
    const int wn = (wave & 1) * (TN / 2);
    const int row16 = lane & 15;
    const int quad  = lane >> 4;
    const int kch   = quad * 8;

    f32x4 acc[4][TN / 32] = {};

    // Staging: ci = q*256 + tid covers a [rows][32] tile row-major
    // (row = ci>>2, kcol = (ci&3)*8); global source contiguous in lane order;
    // LDS dest = wave-uniform base + lane*16B = &tile[ci*8]. 64-B row stride.
    const int r_s = tid >> 2;
    const int c_s = (tid & 3) * 8;
    const size_t aRow0 = (size_t)(m0 + r_s) * lda + c_s;
    const size_t aRow1 = aRow0 + (size_t)64 * lda;
    const size_t bRow0 = (size_t)(n0 + r_s) * ldb + c_s;
    const size_t bRow1 = bRow0 + (size_t)64 * ldb;
    unsigned short* asBase0 = &As[(wave * 64) * 8];
    unsigned short* asBase1 = &As[(256 + wave * 64) * 8];
    unsigned short* bsBase0 = &Bs[(wave * 64) * 8];
    unsigned short* bsBase1 = &Bs[(256 + wave * 64) * 8];

    for (int kt = 0; kt < kIters; ++kt) {
        const int k0 = kt * 32;
        __builtin_amdgcn_global_load_lds(GLOBAL_AS(A + aRow0 + k0), LDS_AS(asBase0), 16, 0, 0);
        __builtin_amdgcn_global_load_lds(GLOBAL_AS(A + aRow1 + k0), LDS_AS(asBase1), 16, 0, 0);
        __builtin_amdgcn_global_load_lds(GLOBAL_AS(Bt + bRow0 + k0), LDS_AS(bsBase0), 16, 0, 0);
        if (TN == 128)
            __builtin_amdgcn_global_load_lds(GLOBAL_AS(Bt + bRow1 + k0), LDS_AS(bsBase1), 16, 0, 0);
        __syncthreads();

        bf16x8 af[4], bfr[TN / 32];
        #pragma unroll
        for (int mi = 0; mi < 4; ++mi)
            af[mi] = *(const bf16x8*)&As[(wm + mi * 16 + row16) * 32 + kch];
        #pragma unroll
        for (int ni = 0; ni < NI; ++ni)
            bfr[ni] = *(const bf16x8*)&Bs[(wn + ni * 16 + row16) * 32 + kch];

        #pragma unroll
        for (int mi = 0; mi < 4; ++mi)
            #pragma unroll
            for (int ni = 0; ni < NI; ++ni)
                acc[mi][ni] = __builtin_amdgcn_mfma_f32_16x16x32_bf16(
                    af[mi], bfr[ni], acc[mi][ni], 0, 0, 0);
        __syncthreads();
    }

    const bool lora = (EPI == 0) && (bx == 24);

    // epilogue: lane holds col = row16 (+16*ni), rows quad*4 + i
    #pragma unroll
    for (int mi = 0; mi < 4; ++mi) {
        #pragma unroll
        for (int i = 0; i < 4; ++i) {
            const int m = m0 + wm + mi * 16 + quad * 4 + i;
            int i0 = 0, i1 = 0; float p0 = 0.f, p1 = 0.f;
            if (EPI == 0 && lora) {
                i0 = tki[m * 2]; i1 = tki[m * 2 + 1];
                p0 = tkp[m * 2]; p1 = tkp[m * 2 + 1];
            }
            #pragma unroll
            for (int ni = 0; ni < NI; ++ni) {
                const int ncol = n0 + wn + ni * 16 + row16;
                float v = acc[mi][ni][i];
                if (EPI == 0) {
                    if (lora) {
                        const int e = (ncol >> 4) - 192;   // (ncol-3072)/16
                        float wt = (i0 == e ? p0 : 0.f) + (i1 == e ? p1 : 0.f);
                        v = gelu_fast(v) * wt;
                    } else {
                        v = gelu_fast(v + bias[ncol]);
                    }
                    apOut[(size_t)m * KBIG + ncol] = f2bf(v);
                } else {
                    fOut[(size_t)m * CDIM + ncol] = v + bias[ncol];
                }
            }
        }
    }
}

// ---------------- launch ----------------

extern "C" void kernel_launch(void* const* d_in, const int* in_sizes, int n_in,
                              void* d_out, int out_size, void* d_ws, size_t ws_size,
                              hipStream_t stream) {
    const float* x   = (const float*)d_in[0];
    const float* tkp = (const float*)d_in[1];
    const int*   tki = (const int*)d_in[2];
    const float* w1  = (const float*)d_in[3];
    const float* b1  = (const float*)d_in[4];
    const float* w2  = (const float*)d_in[5];
    const float* b2  = (const float*)d_in[6];
    const float* wdn = (const float*)d_in[7];
    const float* wup = (const float*)d_in[8];
    float* out = (float*)d_out;

    unsigned short* xb  = (unsigned short*)d_ws;
    unsigned short* w1t = xb  + (size_t)NTOK * CDIM;      // 3200 rows x 768 (w1t | wdt)
    unsigned short* wdt = w1t + (size_t)HIDDIM * CDIM;    // rows 3072..3199
    unsigned short* B2t = w1t + (size_t)KBIG * CDIM;      // 768 x 3200
    unsigned short* Ap  = B2t + (size_t)CDIM * KBIG;      // 12544 x 3200

    prep_kernel<<<dim3(14496), 256, 0, stream>>>(x, w1, w2, wup, wdn,
                                                 xb, w1t, B2t, wdt);

    // GEMM1 (+LoRA tail rows): grid 24x103 — width stays 8-aligned (R7 fix)
    gemm_bt_kernel<0, 128><<<dim3(24, 103), 256, 0, stream>>>(
        xb, CDIM, w1t, CDIM, CDIM / 32, b1, Ap, nullptr, tki, tkp);

    // GEMM2: out = Ap @ B2t^T + b2 ; K=3200 -> 100 BK32 iters; XCD-swizzled grid
    gemm_bt_kernel<2, 64><<<dim3(1248), 256, 0, stream>>>(
        Ap, KBIG, B2t, KBIG, KBIG / 32, b2, nullptr, out, nullptr, nullptr);
}

// Round 8
// 333.304 us; speedup vs baseline: 1.1748x; 1.1604x over previous
//
#include <hip/hip_runtime.h>
#include <hip/hip_bf16.h>
#include <math.h>

// ConvNeXt MLP + parallel MoE-LoRA, fp32 in/out, bf16-tolerance harness.
// B,H,W,C = 64,14,14,768 ; N_tok = 12544 = 98*128 ; HID = 3072 ; E=8,K=2,R=16.
//
//   h  = gelu(x @ w1 + b1)                GEMM1  [12544,768]x[768,3072]
//   sd = wt * gelu(x @ wdown)             GEMMd  [12544,768]x[768,128]
//   out = [h | sd] @ [w2 ; wup] + b2      GEMM2  [12544,3200]x[3200,768]
//
// R8: FULL revert to the R3-proven GEMM config. Evidence across R4-R7:
//  - LoRA fold into GEMM1 raised VGPR 84->108 and cost ~60% duration
//    (Occ 27->21%; latency-bound kernel, waves/SIMD floor(512/VGPR) 6->4).
//    => GEMMd stays a separate clean kernel; GEMM1 is branch-free EPI0.
//  - GEMM2 TN=64 regressed ~110->~170 us (halved MFMA per staging round).
//    => TN=128 + 1-D XCD swizzle (624 blocks), the R3 winner.
//  - LDS: BK=32, 64-B row stride, contiguous global staging (R5's 128-B
//    stride tripled bank conflicts; R4's source swizzle doubled FETCH).
//  Kept from R4+: single fused prep dispatch; gelu_fast (R3 win).

#define NTOK   12544
#define CDIM   768
#define HIDDIM 3072
#define KBIG   3200

typedef __attribute__((ext_vector_type(8))) short bf16x8;
typedef __attribute__((ext_vector_type(4))) float f32x4;

#define GLOBAL_AS(p) ((const __attribute__((address_space(1))) void*)(p))
#define LDS_AS(p)    ((__attribute__((address_space(3))) void*)(p))

__device__ inline unsigned short f2bf(float f) {
    unsigned int x = __float_as_uint(f);
    x += 0x7fffu + ((x >> 16) & 1u);   // RNE
    return (unsigned short)(x >> 16);
}

// tanh-form GELU, branch-free; max |err| ~4.3e-4 vs exact erf form.
__device__ inline float gelu_fast(float x) {
    float x3 = x * x * x;
    float u2 = 1.5957691216057308f * x + 0.07135481627260025f * x3;
    float e = __expf(-u2);
    return x * __builtin_amdgcn_rcpf(1.0f + e);
}

// ---------------- fused prep: cast_x + 3 transposes + pack_wdown ----------------
__global__ void __launch_bounds__(256) prep_kernel(
        const float* __restrict__ x, const float* __restrict__ w1,
        const float* __restrict__ w2, const float* __restrict__ wup,
        const float* __restrict__ wdn,
        unsigned short* __restrict__ xb, unsigned short* __restrict__ w1t,
        unsigned short* __restrict__ B2t, unsigned short* __restrict__ wdt) {
    __shared__ float tile[32][33];
    const int b = blockIdx.x, tid = threadIdx.x;
    if (b < 9408) {                      // cast x -> bf16, float4->ushort4
        int i = b * 256 + tid;
        float4 v = ((const float4*)x)[i];
        ushort4 o;
        o.x = f2bf(v.x); o.y = f2bf(v.y); o.z = f2bf(v.z); o.w = f2bf(v.w);
        ((ushort4*)xb)[i] = o;
        return;
    }
    if (b < 14112) {                     // 32x32 transpose tiles
        const float* in; unsigned short* outp; int Ccols, out_ld, out_off, bx, by;
        if (b < 11712) { int t = b - 9408;  in = w1;  outp = w1t; Ccols = 3072; out_ld = 768;  out_off = 0;    bx = t % 96; by = t / 96; }
        else if (b < 14016) { int t = b - 11712; in = w2;  outp = B2t; Ccols = 768;  out_ld = 3200; out_off = 0;    bx = t % 24; by = t / 24; }
        else { int t = b - 14016; in = wup; outp = B2t; Ccols = 768;  out_ld = 3200; out_off = 3072; bx = t % 24; by = t / 24; }
        int c0 = bx * 32, r0 = by * 32;
        int tx = tid & 31, ty = tid >> 5;
        for (int i = ty; i < 32; i += 8)
            tile[i][tx] = in[(size_t)(r0 + i) * Ccols + c0 + tx];
        __syncthreads();
        for (int i = ty; i < 32; i += 8)
            outp[(size_t)(c0 + i) * out_ld + out_off + r0 + tx] = f2bf(tile[tx][i]);
        return;
    }
    {   // pack_wdown: wdt[j][c] = wdown[e][c][r], j = e*16+r
        int idx = (b - 14112) * 256 + tid;
        int j = idx / 768, c = idx - j * 768;
        int e = j >> 4, r = j & 15;
        wdt[idx] = f2bf(wdn[((size_t)e * 768 + c) * 16 + r]);
    }
}

// ---------------- MFMA GEMM, C = A * Bt^T, 128x128 tile, BK=32 (R3 core) ------
// EPI 0: gelu(acc + b1[n]) -> bf16 Ap[m*3200 + n]
// EPI 1: wt[m, n>>4]*gelu(acc) -> bf16 Ap[m*3200 + 3072 + n]
// EPI 2: acc + b2[n] -> f32 out[m*768 + n]  (1-D grid + XCD swizzle)

template <int EPI>
__global__ void __launch_bounds__(256)
gemm_bt_kernel(const unsigned short* __restrict__ A, int lda,
               const unsigned short* __restrict__ Bt, int ldb,
               int kIters,
               const float* __restrict__ bias,
               unsigned short* __restrict__ apOut,
               float* __restrict__ fOut,
               const int* __restrict__ tki,
               const float* __restrict__ tkp) {
    __shared__ __align__(16) unsigned short As[128 * 32];
    __shared__ __align__(16) unsigned short Bs[128 * 32];

    int bx, by;
    if (EPI == 2) {
        // 624 blocks; same-m-row blocks share L&7 -> same XCD, consecutive.
        int L = blockIdx.x;
        int k = L & 7, t = L >> 3;
        bx = t % 6;
        by = (t / 6) * 8 + k;
        if (by >= NTOK / 128) return;      // block-uniform, pre-barrier safe
    } else {
        bx = blockIdx.x;
        by = blockIdx.y;
    }

    const int tid  = threadIdx.x;
    const int wave = tid >> 6;
    const int lane = tid & 63;
    const int m0 = by * 128;
    const int n0 = bx * 128;
    const int wm = (wave >> 1) * 64;
    const int wn = (wave & 1) * 64;
    const int row16 = lane & 15;
    const int quad  = lane >> 4;
    const int kch   = quad * 8;

    f32x4 acc[4][4] = {};

    // Staging: ci = q*256 + tid covers the 128x32 tile row-major (row=ci>>2,
    // kcol=(ci&3)*8); global source contiguous in lane order; LDS dest =
    // wave-uniform base + lane*16B = &tile[ci*8]. 64-B row stride (2-bank).
    const int r_s = tid >> 2;
    const int c_s = (tid & 3) * 8;
    const size_t aRow0 = (size_t)(m0 + r_s) * lda + c_s;
    const size_t aRow1 = aRow0 + (size_t)64 * lda;
    const size_t bRow0 = (size_t)(n0 + r_s) * ldb + c_s;
    const size_t bRow1 = bRow0 + (size_t)64 * ldb;
    unsigned short* asBase0 = &As[(wave * 64) * 8];
    unsigned short* asBase1 = &As[(256 + wave * 64) * 8];
    unsigned short* bsBase0 = &Bs[(wave * 64) * 8];
    unsigned short* bsBase1 = &Bs[(256 + wave * 64) * 8];

    for (int kt = 0; kt < kIters; ++kt) {
        const int k0 = kt * 32;
        __builtin_amdgcn_global_load_lds(GLOBAL_AS(A + aRow0 + k0), LDS_AS(asBase0), 16, 0, 0);
        __builtin_amdgcn_global_load_lds(GLOBAL_AS(A + aRow1 + k0), LDS_AS(asBase1), 16, 0, 0);
        __builtin_amdgcn_global_load_lds(GLOBAL_AS(Bt + bRow0 + k0), LDS_AS(bsBase0), 16, 0, 0);
        __builtin_amdgcn_global_load_lds(GLOBAL_AS(Bt + bRow1 + k0), LDS_AS(bsBase1), 16, 0, 0);
        __syncthreads();

        bf16x8 af[4], bfr[4];
        #pragma unroll
        for (int mi = 0; mi < 4; ++mi)
            af[mi] = *(const bf16x8*)&As[(wm + mi * 16 + row16) * 32 + kch];
        #pragma unroll
        for (int ni = 0; ni < 4; ++ni)
            bfr[ni] = *(const bf16x8*)&Bs[(wn + ni * 16 + row16) * 32 + kch];

        #pragma unroll
        for (int mi = 0; mi < 4; ++mi)
            #pragma unroll
            for (int ni = 0; ni < 4; ++ni)
                acc[mi][ni] = __builtin_amdgcn_mfma_f32_16x16x32_bf16(
                    af[mi], bfr[ni], acc[mi][ni], 0, 0, 0);
        __syncthreads();
    }

    // epilogue: lane holds col = row16 (+16*ni), rows quad*4 + i
    #pragma unroll
    for (int mi = 0; mi < 4; ++mi) {
        #pragma unroll
        for (int i = 0; i < 4; ++i) {
            const int m = m0 + wm + mi * 16 + quad * 4 + i;
            int i0 = 0, i1 = 0; float p0 = 0.f, p1 = 0.f;
            if (EPI == 1) {
                i0 = tki[m * 2]; i1 = tki[m * 2 + 1];
                p0 = tkp[m * 2]; p1 = tkp[m * 2 + 1];
            }
            #pragma unroll
            for (int ni = 0; ni < 4; ++ni) {
                const int ncol = n0 + wn + ni * 16 + row16;
                float v = acc[mi][ni][i];
                if (EPI == 0) {
                    v = gelu_fast(v + bias[ncol]);
                    apOut[(size_t)m * KBIG + ncol] = f2bf(v);
                } else if (EPI == 1) {
                    const int e = ncol >> 4;
                    float wt = (i0 == e ? p0 : 0.f) + (i1 == e ? p1 : 0.f);
                    v = gelu_fast(v) * wt;
                    apOut[(size_t)m * KBIG + 3072 + ncol] = f2bf(v);
                } else {
                    fOut[(size_t)m * CDIM + ncol] = v + bias[ncol];
                }
            }
        }
    }
}

// ---------------- launch ----------------

extern "C" void kernel_launch(void* const* d_in, const int* in_sizes, int n_in,
                              void* d_out, int out_size, void* d_ws, size_t ws_size,
                              hipStream_t stream) {
    const float* x   = (const float*)d_in[0];
    const float* tkp = (const float*)d_in[1];
    const int*   tki = (const int*)d_in[2];
    const float* w1  = (const float*)d_in[3];
    const float* b1  = (const float*)d_in[4];
    const float* w2  = (const float*)d_in[5];
    const float* b2  = (const float*)d_in[6];
    const float* wdn = (const float*)d_in[7];
    const float* wup = (const float*)d_in[8];
    float* out = (float*)d_out;

    unsigned short* xb  = (unsigned short*)d_ws;
    unsigned short* w1t = xb  + (size_t)NTOK * CDIM;      // 3072 x 768
    unsigned short* B2t = w1t + (size_t)HIDDIM * CDIM;    // 768 x 3200
    unsigned short* wdt = B2t + (size_t)CDIM * KBIG;      // 128 x 768
    unsigned short* Ap  = wdt + (size_t)128 * CDIM;       // 12544 x 3200

    prep_kernel<<<dim3(14496), 256, 0, stream>>>(x, w1, w2, wup, wdn,
                                                 xb, w1t, B2t, wdt);

    // GEMMd: sd -> Ap[:, 3072:3200] ; 98 blocks
    gemm_bt_kernel<1><<<dim3(1, NTOK / 128), 256, 0, stream>>>(
        xb, CDIM, wdt, CDIM, CDIM / 32, nullptr, Ap, nullptr, tki, tkp);
    // GEMM1: h -> Ap[:, 0:3072] ; grid (24, 98) — R3-proven
    gemm_bt_kernel<0><<<dim3(HIDDIM / 128, NTOK / 128), 256, 0, stream>>>(
        xb, CDIM, w1t, CDIM, CDIM / 32, b1, Ap, nullptr, nullptr, nullptr);
    // GEMM2: out = Ap @ B2t^T + b2 ; 624-block XCD-swizzled grid — R3-proven
    gemm_bt_kernel<2><<<dim3(624), 256, 0, stream>>>(
        Ap, KBIG, B2t, KBIG, KBIG / 32, b2, nullptr, out, nullptr, nullptr);
}